// Round 6
// baseline (232.429 us; speedup 1.0000x reference)
//
#include <hip/hip_runtime.h>

typedef __attribute__((ext_vector_type(8))) __bf16 bf16x8;
typedef __attribute__((ext_vector_type(4))) float f32x4;
typedef unsigned int u32;
typedef unsigned long long u64;
typedef unsigned short u16;

#define NB 131072   // batch
#define TPB 4       // row-tiles per block; grid = 512 (2 blocks/CU)

__device__ __forceinline__ u16 f2bf(float f) {
  unsigned int u = __builtin_bit_cast(unsigned int, f);
  u += 0x7fffu + ((u >> 16) & 1u);
  return (u16)(u >> 16);
}

// pack 2 f32 -> 2 bf16 in one VALU op (RTNE on gfx950)
__device__ __forceinline__ u32 cvt_pk(float lo, float hi) {
  u32 r;
  asm("v_cvt_pk_bf16_f32 %0, %1, %2" : "=v"(r) : "v"(lo), "v"(hi));
  return r;
}

// XOR-swizzled LDS addressing (T2)
#define INP_ADDR(r, byte) (((r) << 8) + ((byte) ^ (((r) & 7) << 4)))   // 256 B/row
#define X_ADDR(r, byte)   (((r) << 9) + ((byte) ^ (((r) & 7) << 4)))   // 512 B/row

// ---------------- prep: bf16 frag-ordered weights + per-pair fused bias ----------------
// ws layout: W1f @0 (64KB), W2f @65536 (128KB), Whf @196608 (64KB), b1p @262144 (3KB)
__global__ void prep_kernel(const float* __restrict__ W1, const float* __restrict__ b1,
                            const float* __restrict__ W2,
                            const float* __restrict__ Wm, const float* __restrict__ Wv,
                            u16* __restrict__ W1f, u16* __restrict__ W2f,
                            u16* __restrict__ Whf, float* __restrict__ b1p) {
  int tid = blockIdx.x * 256 + threadIdx.x;
  int NT = gridDim.x * 256;
  for (int i = tid; i < 32768; i += NT) {   // W1f: frag f = kf*16+nf
    int j = i & 7, lane = (i >> 3) & 63, f = i >> 9;
    int nf = f & 15, kf = f >> 4;
    int n = nf * 16 + (lane & 15);
    int k = kf * 32 + 8 * (lane >> 4) + j;
    W1f[i] = f2bf(W1[k * 256 + n]);
  }
  for (int i = tid; i < 65536; i += NT) {   // W2f: f = kf*16+nf
    int j = i & 7, lane = (i >> 3) & 63, f = i >> 9;
    int nf = f & 15, kf = f >> 4;
    int n = nf * 16 + (lane & 15);
    int k = kf * 32 + 8 * (lane >> 4) + j;
    W2f[i] = f2bf(W2[k * 256 + n]);
  }
  for (int i = tid; i < 32768; i += NT) {   // Whf = [Wm | Wv]: f = kf*8+nf
    int j = i & 7, lane = (i >> 3) & 63, f = i >> 9;
    int nf = f & 7, kf = f >> 3;
    int n = nf * 16 + (lane & 15);
    int k = kf * 32 + 8 * (lane >> 4) + j;
    Whf[i] = f2bf(n < 64 ? Wm[k * 64 + n] : Wv[k * 64 + (n - 64)]);
  }
  if (tid < 768) {                          // pairs (0,1),(0,2),(1,2) -> W1 rows {0,4},{0,5},{1,5}
    int p = tid >> 8, h = tid & 255;
    const int r1[3] = {0, 0, 1};
    const int r2[3] = {4, 5, 5};
    b1p[tid] = b1[h] + W1[r1[p] * 256 + h] + W1[r2[p] * 256 + h];
  }
}

// ---- fused encoder: 8 waves, swapped MFMA, weights streamed from L2, 2 blocks/CU ----
__global__ __launch_bounds__(512, 4) void fused_kernel(
    const float* __restrict__ init_s, const float* __restrict__ cur_s,
    const float* __restrict__ emb,
    const u16* __restrict__ W1f, const u16* __restrict__ W2f,
    const u16* __restrict__ Whf,
    const float* __restrict__ b1p, const float* __restrict__ b2,
    const float* __restrict__ bm, const float* __restrict__ bv,
    float* __restrict__ out) {
  extern __shared__ char smem[];
  char* inp = smem;            // [64][128] bf16 swizzled (16 KB)
  char* x1  = smem + 16384;    // [64][256] bf16 swizzled (32 KB)
  char* x2  = smem + 49152;    // [64][256] bf16 swizzled (32 KB)   total = 80 KB exact

  const int t = threadIdx.x;
  const int lane = t & 63;
  const int wave = t >> 6;     // 0..7: owns 32 n-cols of L1/L2, 16 head cols
  const int ql = lane & 15, qw = lane >> 4;

  // head constants (resident: 4 regs + ptr)
  const int hn = wave * 16 + qw * 4;
  const f32x4 hb = (hn < 64) ? *(const f32x4*)(bm + hn) : *(const f32x4*)(bv + hn - 64);
  float* const hout = (hn < 64) ? (out + hn) : (out + (size_t)3 * NB * 64 + (hn - 64));

  const int IA[3] = {0, 1, 2};
  const int IB[3] = {3, 5, 7};
  const int IC[3] = {4, 6, 8};

  // ---- prologue: one-hot zeros + stage tile 0 / pair 0 ----
  if (t < 64) {
    *(u64*)(inp + INP_ADDR(t, 0)) = 0ull;
    *(u32*)(inp + INP_ADDR(t, 8)) = 0u;
  }
  {
    const size_t nb0 = (size_t)blockIdx.x * TPB * 64;
    for (int i = t; i < 64 * 29; i += 512) {
      int r = i / 29, c4 = i - r * 29;
      const float4 v = *(const float4*)(emb + (nb0 + r) * 116 + c4 * 4);
      u64 pk = (u64)cvt_pk(v.x, v.y) | ((u64)cvt_pk(v.z, v.w) << 32);
      *(u64*)(inp + INP_ADDR(r, 24 + 8 * c4)) = pk;
    }
    if (t < 64) {
      const float* isr = init_s + (nb0 + t) * 9;
      const float* csr = cur_s + (nb0 + t) * 9;
      *(u32*)(inp + INP_ADDR(t, 12)) = cvt_pk(isr[0], isr[3]);
      *(u32*)(inp + INP_ADDR(t, 16)) = cvt_pk(isr[4], csr[0]);
      *(u32*)(inp + INP_ADDR(t, 20)) = cvt_pk(csr[3], csr[4]);
    }
  }
  __syncthreads();  // BAR1: inp ready

#pragma unroll 1
  for (int step = 0; step < 3 * TPB; ++step) {
    const int p = step % 3;
    const size_t b0 = (size_t)(blockIdx.x * TPB + step / 3) * 64;

    // ---- Phase B: layer 1 (read inp, W1 from L2; write x1) ----
    {
      f32x4 acc[4][2];
#pragma unroll
      for (int ni = 0; ni < 2; ++ni) {
        f32x4 bb = *(const f32x4*)(b1p + p * 256 + wave * 32 + ni * 16 + qw * 4);
#pragma unroll
        for (int bf = 0; bf < 4; ++bf) acc[bf][ni] = bb;
      }
#pragma unroll
      for (int kf = 0; kf < 4; ++kf) {
        bf16x8 w0 = *(const bf16x8*)(W1f + (size_t)((kf * 16 + wave * 2 + 0) * 64 + lane) * 8);
        bf16x8 w1 = *(const bf16x8*)(W1f + (size_t)((kf * 16 + wave * 2 + 1) * 64 + lane) * 8);
        bf16x8 a[4];
#pragma unroll
        for (int bf = 0; bf < 4; ++bf)
          a[bf] = *(const bf16x8*)(inp + INP_ADDR(bf * 16 + ql, kf * 64 + qw * 16));
#pragma unroll
        for (int bf = 0; bf < 4; ++bf)
          acc[bf][0] = __builtin_amdgcn_mfma_f32_16x16x32_bf16(w0, a[bf], acc[bf][0], 0, 0, 0);
#pragma unroll
        for (int bf = 0; bf < 4; ++bf)
          acc[bf][1] = __builtin_amdgcn_mfma_f32_16x16x32_bf16(w1, a[bf], acc[bf][1], 0, 0, 0);
      }
#pragma unroll
      for (int bf = 0; bf < 4; ++bf)
#pragma unroll
        for (int ni = 0; ni < 2; ++ni) {
          f32x4 v = acc[bf][ni];
          u64 pk = (u64)cvt_pk(fmaxf(v[0], 0.f), fmaxf(v[1], 0.f))
                 | ((u64)cvt_pk(fmaxf(v[2], 0.f), fmaxf(v[3], 0.f)) << 32);
          *(u64*)(x1 + X_ADDR(bf * 16 + ql, wave * 64 + ni * 32 + qw * 8)) = pk;
        }
    }
    __syncthreads();  // BAR2: x1 ready

    // ---- Phase C: layer 2 (read x1, W2 from L2; write x2) ----
    {
      f32x4 acc[4][2];
#pragma unroll
      for (int ni = 0; ni < 2; ++ni) {
        f32x4 bb = *(const f32x4*)(b2 + wave * 32 + ni * 16 + qw * 4);
#pragma unroll
        for (int bf = 0; bf < 4; ++bf) acc[bf][ni] = bb;
      }
#pragma unroll 4
      for (int kf = 0; kf < 8; ++kf) {
        bf16x8 w0 = *(const bf16x8*)(W2f + (size_t)((kf * 16 + wave * 2 + 0) * 64 + lane) * 8);
        bf16x8 w1 = *(const bf16x8*)(W2f + (size_t)((kf * 16 + wave * 2 + 1) * 64 + lane) * 8);
        bf16x8 a[4];
#pragma unroll
        for (int bf = 0; bf < 4; ++bf)
          a[bf] = *(const bf16x8*)(x1 + X_ADDR(bf * 16 + ql, kf * 64 + qw * 16));
#pragma unroll
        for (int bf = 0; bf < 4; ++bf)
          acc[bf][0] = __builtin_amdgcn_mfma_f32_16x16x32_bf16(w0, a[bf], acc[bf][0], 0, 0, 0);
#pragma unroll
        for (int bf = 0; bf < 4; ++bf)
          acc[bf][1] = __builtin_amdgcn_mfma_f32_16x16x32_bf16(w1, a[bf], acc[bf][1], 0, 0, 0);
      }
#pragma unroll
      for (int bf = 0; bf < 4; ++bf)
#pragma unroll
        for (int ni = 0; ni < 2; ++ni) {
          f32x4 v = acc[bf][ni];
          u64 pk = (u64)cvt_pk(fmaxf(v[0], 0.f), fmaxf(v[1], 0.f))
                 | ((u64)cvt_pk(fmaxf(v[2], 0.f), fmaxf(v[3], 0.f)) << 32);
          *(u64*)(x2 + X_ADDR(bf * 16 + ql, wave * 64 + ni * 32 + qw * 8)) = pk;
        }
    }
    __syncthreads();  // BAR3: x2 ready

    // ---- Phase A: heads (read x2, Wh from L2; store to global) + stage next pair ----
    {
      f32x4 hacc[4];
#pragma unroll
      for (int bf = 0; bf < 4; ++bf) hacc[bf] = hb;
#pragma unroll
      for (int kf = 0; kf < 8; ++kf) {
        bf16x8 w = *(const bf16x8*)(Whf + (size_t)((kf * 8 + wave) * 64 + lane) * 8);
        bf16x8 a[4];
#pragma unroll
        for (int bf = 0; bf < 4; ++bf)
          a[bf] = *(const bf16x8*)(x2 + X_ADDR(bf * 16 + ql, kf * 64 + qw * 16));
#pragma unroll
        for (int bf = 0; bf < 4; ++bf)
          hacc[bf] = __builtin_amdgcn_mfma_f32_16x16x32_bf16(w, a[bf], hacc[bf], 0, 0, 0);
      }
#pragma unroll
      for (int bf = 0; bf < 4; ++bf)
        *(f32x4*)(hout + ((size_t)p * NB + b0 + bf * 16 + ql) * 64) = hacc[bf];

      // stage inp for next step (s-cols; + embeddings at tile boundary)
      if (step + 1 < 3 * TPB) {
        const int np = (step + 1) % 3;
        const size_t nb0 = (size_t)(blockIdx.x * TPB + (step + 1) / 3) * 64;
        if (np == 0) {
          for (int i = t; i < 64 * 29; i += 512) {
            int r = i / 29, c4 = i - r * 29;
            const float4 v = *(const float4*)(emb + (nb0 + r) * 116 + c4 * 4);
            u64 pk = (u64)cvt_pk(v.x, v.y) | ((u64)cvt_pk(v.z, v.w) << 32);
            *(u64*)(inp + INP_ADDR(r, 24 + 8 * c4)) = pk;
          }
        }
        if (t < 64) {
          const float* isr = init_s + (nb0 + t) * 9;
          const float* csr = cur_s + (nb0 + t) * 9;
          *(u32*)(inp + INP_ADDR(t, 12)) = cvt_pk(isr[IA[np]], isr[IB[np]]);
          *(u32*)(inp + INP_ADDR(t, 16)) = cvt_pk(isr[IC[np]], csr[IA[np]]);
          *(u32*)(inp + INP_ADDR(t, 20)) = cvt_pk(csr[IB[np]], csr[IC[np]]);
        }
      }
    }
    __syncthreads();  // BAR1: inp ready for next step
  }
}

extern "C" void kernel_launch(void* const* d_in, const int* in_sizes, int n_in,
                              void* d_out, int out_size, void* d_ws, size_t ws_size,
                              hipStream_t stream) {
  (void)in_sizes; (void)n_in; (void)out_size; (void)ws_size;
  const float* init_s = (const float*)d_in[0];
  const float* cur_s  = (const float*)d_in[1];
  const float* emb    = (const float*)d_in[2];
  const float* W1 = (const float*)d_in[3];
  const float* b1 = (const float*)d_in[4];
  const float* W2 = (const float*)d_in[5];
  const float* b2 = (const float*)d_in[6];
  const float* Wm = (const float*)d_in[7];
  const float* bm = (const float*)d_in[8];
  const float* Wv = (const float*)d_in[9];
  const float* bv = (const float*)d_in[10];

  u16* W1f = (u16*)d_ws;
  u16* W2f = (u16*)((char*)d_ws + 65536);
  u16* Whf = (u16*)((char*)d_ws + 196608);
  float* b1p = (float*)((char*)d_ws + 262144);

  prep_kernel<<<128, 256, 0, stream>>>(W1, b1, W2, Wm, Wv, W1f, W2f, Whf, b1p);

  const int lds_bytes = 16384 + 32768 + 32768;  // 80 KB exact -> 2 blocks/CU
  (void)hipFuncSetAttribute((const void*)fused_kernel,
                            hipFuncAttributeMaxDynamicSharedMemorySize, lds_bytes);
  fused_kernel<<<NB / (64 * TPB), 512, lds_bytes, stream>>>(init_s, cur_s, emb, W1f, W2f, Whf,
                                                            b1p, b2, bm, bv, (float*)d_out);
}

// Round 7
// 228.677 us; speedup vs baseline: 1.0164x; 1.0164x over previous
//
#include <hip/hip_runtime.h>

typedef __attribute__((ext_vector_type(8))) __bf16 bf16x8;
typedef __attribute__((ext_vector_type(4))) float f32x4;
typedef unsigned int u32;
typedef unsigned long long u64;
typedef unsigned short u16;

#define NB 131072   // batch
#define TPB 4       // row-tiles per block; grid = 512 (2 blocks/CU)

__device__ __forceinline__ u16 f2bf(float f) {
  unsigned int u = __builtin_bit_cast(unsigned int, f);
  u += 0x7fffu + ((u >> 16) & 1u);
  return (u16)(u >> 16);
}

// pack 2 f32 -> 2 bf16 in one VALU op (RTNE on gfx950)
__device__ __forceinline__ u32 cvt_pk(float lo, float hi) {
  u32 r;
  asm("v_cvt_pk_bf16_f32 %0, %1, %2" : "=v"(r) : "v"(lo), "v"(hi));
  return r;
}

// XOR-swizzled LDS addressing (T2)
#define INP_ADDR(r, byte) (((r) << 8) + ((byte) ^ (((r) & 7) << 4)))   // 256 B/row
#define X_ADDR(r, byte)   (((r) << 9) + ((byte) ^ (((r) & 7) << 4)))   // 512 B/row

// ---------------- prep: bf16 frag-ordered weights + per-pair fused bias ----------------
// ws layout: W1f @0 (64KB), W2f @65536 (128KB), Whf @196608 (64KB), b1p @262144 (3KB)
__global__ void prep_kernel(const float* __restrict__ W1, const float* __restrict__ b1,
                            const float* __restrict__ W2,
                            const float* __restrict__ Wm, const float* __restrict__ Wv,
                            u16* __restrict__ W1f, u16* __restrict__ W2f,
                            u16* __restrict__ Whf, float* __restrict__ b1p) {
  int tid = blockIdx.x * 256 + threadIdx.x;
  int NT = gridDim.x * 256;
  for (int i = tid; i < 32768; i += NT) {   // W1f: frag f = kf*16+nf
    int j = i & 7, lane = (i >> 3) & 63, f = i >> 9;
    int nf = f & 15, kf = f >> 4;
    int n = nf * 16 + (lane & 15);
    int k = kf * 32 + 8 * (lane >> 4) + j;
    W1f[i] = f2bf(W1[k * 256 + n]);
  }
  for (int i = tid; i < 65536; i += NT) {   // W2f: f = kf*16+nf
    int j = i & 7, lane = (i >> 3) & 63, f = i >> 9;
    int nf = f & 15, kf = f >> 4;
    int n = nf * 16 + (lane & 15);
    int k = kf * 32 + 8 * (lane >> 4) + j;
    W2f[i] = f2bf(W2[k * 256 + n]);
  }
  for (int i = tid; i < 32768; i += NT) {   // Whf = [Wm | Wv]: f = kf*8+nf
    int j = i & 7, lane = (i >> 3) & 63, f = i >> 9;
    int nf = f & 7, kf = f >> 3;
    int n = nf * 16 + (lane & 15);
    int k = kf * 32 + 8 * (lane >> 4) + j;
    Whf[i] = f2bf(n < 64 ? Wm[k * 64 + n] : Wv[k * 64 + (n - 64)]);
  }
  if (tid < 768) {                          // pairs (0,1),(0,2),(1,2) -> W1 rows {0,4},{0,5},{1,5}
    int p = tid >> 8, h = tid & 255;
    const int r1[3] = {0, 0, 1};
    const int r2[3] = {4, 5, 5};
    b1p[tid] = b1[h] + W1[r1[p] * 256 + h] + W1[r2[p] * 256 + h];
  }
}

// ---- fused encoder: 8 waves, swapped MFMA, streamed weights, LDS-staged export, 2 blocks/CU ----
__global__ __launch_bounds__(512, 4) void fused_kernel(
    const float* __restrict__ init_s, const float* __restrict__ cur_s,
    const float* __restrict__ emb,
    const u16* __restrict__ W1f, const u16* __restrict__ W2f,
    const u16* __restrict__ Whf,
    const float* __restrict__ b1p, const float* __restrict__ b2,
    const float* __restrict__ bm, const float* __restrict__ bv,
    float* __restrict__ out) {
  extern __shared__ char smem[];
  char* inp = smem;            // [64][128] bf16 swizzled (16 KB)
  char* x1  = smem + 16384;    // [64][256] bf16 swizzled (32 KB)
  char* x2  = smem + 49152;    // [64][256] bf16 swizzled (32 KB)   total = 80 KB exact
  char* ost = x1;              // [64 batch][128 hcol] f32 swizzled, aliases x1 (dead by heads)

  const int t = threadIdx.x;
  const int lane = t & 63;
  const int wave = t >> 6;     // 0..7: owns 32 n-cols of L1/L2, 16 head cols
  const int ql = lane & 15, qw = lane >> 4;

  // head bias: n = wave*16 + qw*4 (4 consecutive, never straddles 64)
  const int hn = wave * 16 + qw * 4;
  const f32x4 hb = (hn < 64) ? *(const f32x4*)(bm + hn) : *(const f32x4*)(bv + hn - 64);

  const int IA[3] = {0, 1, 2};
  const int IB[3] = {3, 5, 7};
  const int IC[3] = {4, 6, 8};

  // ---- prologue: one-hot zeros + stage tile 0 / pair 0 ----
  if (t < 64) {
    *(u64*)(inp + INP_ADDR(t, 0)) = 0ull;
    *(u32*)(inp + INP_ADDR(t, 8)) = 0u;
  }
  {
    const size_t nb0 = (size_t)blockIdx.x * TPB * 64;
    for (int i = t; i < 64 * 29; i += 512) {
      int r = i / 29, c4 = i - r * 29;
      const float4 v = *(const float4*)(emb + (nb0 + r) * 116 + c4 * 4);
      u64 pk = (u64)cvt_pk(v.x, v.y) | ((u64)cvt_pk(v.z, v.w) << 32);
      *(u64*)(inp + INP_ADDR(r, 24 + 8 * c4)) = pk;
    }
    if (t < 64) {
      const float* isr = init_s + (nb0 + t) * 9;
      const float* csr = cur_s + (nb0 + t) * 9;
      *(u32*)(inp + INP_ADDR(t, 12)) = cvt_pk(isr[0], isr[3]);
      *(u32*)(inp + INP_ADDR(t, 16)) = cvt_pk(isr[4], csr[0]);
      *(u32*)(inp + INP_ADDR(t, 20)) = cvt_pk(csr[3], csr[4]);
    }
  }
  __syncthreads();  // BAR1: inp ready

#pragma unroll 1
  for (int step = 0; step < 3 * TPB; ++step) {
    const int p = step % 3;
    const size_t b0 = (size_t)(blockIdx.x * TPB + step / 3) * 64;

    // ---- Phase B: layer 1 (read inp, W1 from L2; write x1) ----
    {
      f32x4 acc[4][2];
#pragma unroll
      for (int ni = 0; ni < 2; ++ni) {
        f32x4 bb = *(const f32x4*)(b1p + p * 256 + wave * 32 + ni * 16 + qw * 4);
#pragma unroll
        for (int bf = 0; bf < 4; ++bf) acc[bf][ni] = bb;
      }
#pragma unroll
      for (int kf = 0; kf < 4; ++kf) {
        bf16x8 w0 = *(const bf16x8*)(W1f + (size_t)((kf * 16 + wave * 2 + 0) * 64 + lane) * 8);
        bf16x8 w1 = *(const bf16x8*)(W1f + (size_t)((kf * 16 + wave * 2 + 1) * 64 + lane) * 8);
        bf16x8 a[4];
#pragma unroll
        for (int bf = 0; bf < 4; ++bf)
          a[bf] = *(const bf16x8*)(inp + INP_ADDR(bf * 16 + ql, kf * 64 + qw * 16));
#pragma unroll
        for (int bf = 0; bf < 4; ++bf)
          acc[bf][0] = __builtin_amdgcn_mfma_f32_16x16x32_bf16(w0, a[bf], acc[bf][0], 0, 0, 0);
#pragma unroll
        for (int bf = 0; bf < 4; ++bf)
          acc[bf][1] = __builtin_amdgcn_mfma_f32_16x16x32_bf16(w1, a[bf], acc[bf][1], 0, 0, 0);
      }
#pragma unroll
      for (int bf = 0; bf < 4; ++bf)
#pragma unroll
        for (int ni = 0; ni < 2; ++ni) {
          f32x4 v = acc[bf][ni];
          u64 pk = (u64)cvt_pk(fmaxf(v[0], 0.f), fmaxf(v[1], 0.f))
                 | ((u64)cvt_pk(fmaxf(v[2], 0.f), fmaxf(v[3], 0.f)) << 32);
          *(u64*)(x1 + X_ADDR(bf * 16 + ql, wave * 64 + ni * 32 + qw * 8)) = pk;
        }
    }
    __syncthreads();  // BAR2: x1 ready

    // ---- Phase C: layer 2 (read x1, W2 from L2; write x2) ----
    {
      f32x4 acc[4][2];
#pragma unroll
      for (int ni = 0; ni < 2; ++ni) {
        f32x4 bb = *(const f32x4*)(b2 + wave * 32 + ni * 16 + qw * 4);
#pragma unroll
        for (int bf = 0; bf < 4; ++bf) acc[bf][ni] = bb;
      }
#pragma unroll 4
      for (int kf = 0; kf < 8; ++kf) {
        bf16x8 w0 = *(const bf16x8*)(W2f + (size_t)((kf * 16 + wave * 2 + 0) * 64 + lane) * 8);
        bf16x8 w1 = *(const bf16x8*)(W2f + (size_t)((kf * 16 + wave * 2 + 1) * 64 + lane) * 8);
        bf16x8 a[4];
#pragma unroll
        for (int bf = 0; bf < 4; ++bf)
          a[bf] = *(const bf16x8*)(x1 + X_ADDR(bf * 16 + ql, kf * 64 + qw * 16));
#pragma unroll
        for (int bf = 0; bf < 4; ++bf)
          acc[bf][0] = __builtin_amdgcn_mfma_f32_16x16x32_bf16(w0, a[bf], acc[bf][0], 0, 0, 0);
#pragma unroll
        for (int bf = 0; bf < 4; ++bf)
          acc[bf][1] = __builtin_amdgcn_mfma_f32_16x16x32_bf16(w1, a[bf], acc[bf][1], 0, 0, 0);
      }
#pragma unroll
      for (int bf = 0; bf < 4; ++bf)
#pragma unroll
        for (int ni = 0; ni < 2; ++ni) {
          f32x4 v = acc[bf][ni];
          u64 pk = (u64)cvt_pk(fmaxf(v[0], 0.f), fmaxf(v[1], 0.f))
                 | ((u64)cvt_pk(fmaxf(v[2], 0.f), fmaxf(v[3], 0.f)) << 32);
          *(u64*)(x2 + X_ADDR(bf * 16 + ql, wave * 64 + ni * 32 + qw * 8)) = pk;
        }
    }
    __syncthreads();  // BAR3: x2 ready (x1/ost now dead)

    // ---- Phase A: heads (read x2, Wh from L2) -> ost (LDS, f32) ----
    {
      f32x4 hacc[4];
#pragma unroll
      for (int bf = 0; bf < 4; ++bf) hacc[bf] = hb;
#pragma unroll
      for (int kf = 0; kf < 8; ++kf) {
        bf16x8 w = *(const bf16x8*)(Whf + (size_t)((kf * 8 + wave) * 64 + lane) * 8);
        bf16x8 a[4];
#pragma unroll
        for (int bf = 0; bf < 4; ++bf)
          a[bf] = *(const bf16x8*)(x2 + X_ADDR(bf * 16 + ql, kf * 64 + qw * 16));
#pragma unroll
        for (int bf = 0; bf < 4; ++bf)
          hacc[bf] = __builtin_amdgcn_mfma_f32_16x16x32_bf16(w, a[bf], hacc[bf], 0, 0, 0);
      }
      // thread holds 4 consecutive head cols (f32) at fixed batch -> one b128
#pragma unroll
      for (int bf = 0; bf < 4; ++bf) {
        int row = bf * 16 + ql;                         // batch
        int byte = wave * 64 + qw * 16;                 // hcol*4
        *(f32x4*)(ost + row * 512 + (byte ^ ((row & 7) << 4))) = hacc[bf];
      }
    }
    __syncthreads();  // BAR4: ost ready

    // ---- coalesced export (full 256B rows) + stage next pair ----
    for (int i = t; i < 64 * 32; i += 512) {
      int r = i >> 5, c4 = i & 31;
      float4 v = *(const float4*)(ost + r * 512 + ((c4 * 16) ^ ((r & 7) << 4)));
      size_t off;
      if (c4 < 16)
        off = ((size_t)p * NB + b0 + r) * 64 + (size_t)c4 * 4;
      else
        off = (size_t)3 * NB * 64 + ((size_t)p * NB + b0 + r) * 64 + (size_t)(c4 - 16) * 4;
      *(float4*)(out + off) = v;
    }
    if (step + 1 < 3 * TPB) {
      const int np = (step + 1) % 3;
      const size_t nb0 = (size_t)(blockIdx.x * TPB + (step + 1) / 3) * 64;
      if (np == 0) {
        for (int i = t; i < 64 * 29; i += 512) {
          int r = i / 29, c4 = i - r * 29;
          const float4 v = *(const float4*)(emb + (nb0 + r) * 116 + c4 * 4);
          u64 pk = (u64)cvt_pk(v.x, v.y) | ((u64)cvt_pk(v.z, v.w) << 32);
          *(u64*)(inp + INP_ADDR(r, 24 + 8 * c4)) = pk;
        }
      }
      if (t < 64) {
        const float* isr = init_s + (nb0 + t) * 9;
        const float* csr = cur_s + (nb0 + t) * 9;
        *(u32*)(inp + INP_ADDR(t, 12)) = cvt_pk(isr[IA[np]], isr[IB[np]]);
        *(u32*)(inp + INP_ADDR(t, 16)) = cvt_pk(isr[IC[np]], csr[IA[np]]);
        *(u32*)(inp + INP_ADDR(t, 20)) = cvt_pk(csr[IB[np]], csr[IC[np]]);
      }
    }
    __syncthreads();  // BAR1: inp ready; ost reads done before next x1 writes
  }
}

extern "C" void kernel_launch(void* const* d_in, const int* in_sizes, int n_in,
                              void* d_out, int out_size, void* d_ws, size_t ws_size,
                              hipStream_t stream) {
  (void)in_sizes; (void)n_in; (void)out_size; (void)ws_size;
  const float* init_s = (const float*)d_in[0];
  const float* cur_s  = (const float*)d_in[1];
  const float* emb    = (const float*)d_in[2];
  const float* W1 = (const float*)d_in[3];
  const float* b1 = (const float*)d_in[4];
  const float* W2 = (const float*)d_in[5];
  const float* b2 = (const float*)d_in[6];
  const float* Wm = (const float*)d_in[7];
  const float* bm = (const float*)d_in[8];
  const float* Wv = (const float*)d_in[9];
  const float* bv = (const float*)d_in[10];

  u16* W1f = (u16*)d_ws;
  u16* W2f = (u16*)((char*)d_ws + 65536);
  u16* Whf = (u16*)((char*)d_ws + 196608);
  float* b1p = (float*)((char*)d_ws + 262144);

  prep_kernel<<<128, 256, 0, stream>>>(W1, b1, W2, Wm, Wv, W1f, W2f, Whf, b1p);

  const int lds_bytes = 16384 + 32768 + 32768;  // 80 KB exact -> 2 blocks/CU
  (void)hipFuncSetAttribute((const void*)fused_kernel,
                            hipFuncAttributeMaxDynamicSharedMemorySize, lds_bytes);
  fused_kernel<<<NB / (64 * TPB), 512, lds_bytes, stream>>>(init_s, cur_s, emb, W1f, W2f, Whf,
                                                            b1p, b2, bm, bv, (float*)d_out);
}

// Round 8
// 222.862 us; speedup vs baseline: 1.0429x; 1.0261x over previous
//
#include <hip/hip_runtime.h>

typedef __attribute__((ext_vector_type(8))) __bf16 bf16x8;
typedef __attribute__((ext_vector_type(4))) float f32x4;
typedef unsigned int u32;
typedef unsigned long long u64;
typedef unsigned short u16;

#define NB 131072   // batch
#define TPB 4       // row-tiles per block; grid = 512 (2 blocks/CU)

__device__ __forceinline__ u16 f2bf(float f) {
  unsigned int u = __builtin_bit_cast(unsigned int, f);
  u += 0x7fffu + ((u >> 16) & 1u);
  return (u16)(u >> 16);
}

// pack 2 f32 -> 2 bf16 in one VALU op (RTNE on gfx950)
__device__ __forceinline__ u32 cvt_pk(float lo, float hi) {
  u32 r;
  asm("v_cvt_pk_bf16_f32 %0, %1, %2" : "=v"(r) : "v"(lo), "v"(hi));
  return r;
}

// XOR-swizzled LDS addressing (T2)
#define INP_ADDR(r, byte) (((r) << 8) + ((byte) ^ (((r) & 7) << 4)))   // 256 B/row
#define X_ADDR(r, byte)   (((r) << 9) + ((byte) ^ (((r) & 7) << 4)))   // 512 B/row

// ---------------- prep: bf16 frag-ordered weights + per-pair fused bias ----------------
// ws layout: W1f @0 (64KB), W2f @65536 (128KB), Whf @196608 (64KB), b1p @262144 (3KB)
__global__ void prep_kernel(const float* __restrict__ W1, const float* __restrict__ b1,
                            const float* __restrict__ W2,
                            const float* __restrict__ Wm, const float* __restrict__ Wv,
                            u16* __restrict__ W1f, u16* __restrict__ W2f,
                            u16* __restrict__ Whf, float* __restrict__ b1p) {
  int tid = blockIdx.x * 256 + threadIdx.x;
  int NT = gridDim.x * 256;
  for (int i = tid; i < 32768; i += NT) {   // W1f: frag f = kf*16+nf
    int j = i & 7, lane = (i >> 3) & 63, f = i >> 9;
    int nf = f & 15, kf = f >> 4;
    int n = nf * 16 + (lane & 15);
    int k = kf * 32 + 8 * (lane >> 4) + j;
    W1f[i] = f2bf(W1[k * 256 + n]);
  }
  for (int i = tid; i < 65536; i += NT) {   // W2f: f = kf*16+nf
    int j = i & 7, lane = (i >> 3) & 63, f = i >> 9;
    int nf = f & 15, kf = f >> 4;
    int n = nf * 16 + (lane & 15);
    int k = kf * 32 + 8 * (lane >> 4) + j;
    W2f[i] = f2bf(W2[k * 256 + n]);
  }
  for (int i = tid; i < 32768; i += NT) {   // Whf = [Wm | Wv]: f = kf*8+nf
    int j = i & 7, lane = (i >> 3) & 63, f = i >> 9;
    int nf = f & 7, kf = f >> 3;
    int n = nf * 16 + (lane & 15);
    int k = kf * 32 + 8 * (lane >> 4) + j;
    Whf[i] = f2bf(n < 64 ? Wm[k * 64 + n] : Wv[k * 64 + (n - 64)]);
  }
  if (tid < 768) {                          // pairs (0,1),(0,2),(1,2) -> W1 rows {0,4},{0,5},{1,5}
    int p = tid >> 8, h = tid & 255;
    const int r1[3] = {0, 0, 1};
    const int r2[3] = {4, 5, 5};
    b1p[tid] = b1[h] + W1[r1[p] * 256 + h] + W1[r2[p] * 256 + h];
  }
}

// ---- fused encoder: 8 waves, swapped MFMA, streamed weights (L2-protected via NT I/O) ----
__global__ __launch_bounds__(512, 4) void fused_kernel(
    const float* __restrict__ init_s, const float* __restrict__ cur_s,
    const float* __restrict__ emb,
    const u16* __restrict__ W1f, const u16* __restrict__ W2f,
    const u16* __restrict__ Whf,
    const float* __restrict__ b1p, const float* __restrict__ b2,
    const float* __restrict__ bm, const float* __restrict__ bv,
    float* __restrict__ out) {
  extern __shared__ char smem[];
  char* inp = smem;            // [64][128] bf16 swizzled (16 KB)
  char* x1  = smem + 16384;    // [64][256] bf16 swizzled (32 KB)
  char* x2  = smem + 49152;    // [64][256] bf16 swizzled (32 KB)   total = 80 KB exact
  char* ost = x1;              // [64 batch][128 hcol] f32 swizzled, aliases x1 (dead by heads)

  const int t = threadIdx.x;
  const int lane = t & 63;
  const int wave = t >> 6;     // 0..7: owns 32 n-cols of L1/L2, 16 head cols
  const int ql = lane & 15, qw = lane >> 4;

  // head bias: n = wave*16 + qw*4 (4 consecutive, never straddles 64)
  const int hn = wave * 16 + qw * 4;
  const f32x4 hb = (hn < 64) ? *(const f32x4*)(bm + hn) : *(const f32x4*)(bv + hn - 64);

  const int IA[3] = {0, 1, 2};
  const int IB[3] = {3, 5, 7};
  const int IC[3] = {4, 6, 8};

  // ---- prologue: one-hot zeros + stage tile 0 / pair 0 ----
  if (t < 64) {
    *(u64*)(inp + INP_ADDR(t, 0)) = 0ull;
    *(u32*)(inp + INP_ADDR(t, 8)) = 0u;
  }
  {
    const size_t nb0 = (size_t)blockIdx.x * TPB * 64;
    for (int i = t; i < 64 * 29; i += 512) {
      int r = i / 29, c4 = i - r * 29;
      const f32x4 v = __builtin_nontemporal_load((const f32x4*)(emb + (nb0 + r) * 116 + c4 * 4));
      u64 pk = (u64)cvt_pk(v[0], v[1]) | ((u64)cvt_pk(v[2], v[3]) << 32);
      *(u64*)(inp + INP_ADDR(r, 24 + 8 * c4)) = pk;
    }
    if (t < 64) {
      const float* isr = init_s + (nb0 + t) * 9;
      const float* csr = cur_s + (nb0 + t) * 9;
      *(u32*)(inp + INP_ADDR(t, 12)) = cvt_pk(isr[0], isr[3]);
      *(u32*)(inp + INP_ADDR(t, 16)) = cvt_pk(isr[4], csr[0]);
      *(u32*)(inp + INP_ADDR(t, 20)) = cvt_pk(csr[3], csr[4]);
    }
  }
  __syncthreads();  // BAR1: inp ready

#pragma unroll 1
  for (int step = 0; step < 3 * TPB; ++step) {
    const int p = step % 3;
    const size_t b0 = (size_t)(blockIdx.x * TPB + step / 3) * 64;

    // ---- Phase B: layer 1 (read inp, W1 from L2; write x1) ----
    {
      f32x4 acc[4][2];
#pragma unroll
      for (int ni = 0; ni < 2; ++ni) {
        f32x4 bb = *(const f32x4*)(b1p + p * 256 + wave * 32 + ni * 16 + qw * 4);
#pragma unroll
        for (int bf = 0; bf < 4; ++bf) acc[bf][ni] = bb;
      }
#pragma unroll
      for (int kf = 0; kf < 4; ++kf) {
        bf16x8 w0 = *(const bf16x8*)(W1f + (size_t)((kf * 16 + wave * 2 + 0) * 64 + lane) * 8);
        bf16x8 w1 = *(const bf16x8*)(W1f + (size_t)((kf * 16 + wave * 2 + 1) * 64 + lane) * 8);
        bf16x8 a[4];
#pragma unroll
        for (int bf = 0; bf < 4; ++bf)
          a[bf] = *(const bf16x8*)(inp + INP_ADDR(bf * 16 + ql, kf * 64 + qw * 16));
#pragma unroll
        for (int bf = 0; bf < 4; ++bf)
          acc[bf][0] = __builtin_amdgcn_mfma_f32_16x16x32_bf16(w0, a[bf], acc[bf][0], 0, 0, 0);
#pragma unroll
        for (int bf = 0; bf < 4; ++bf)
          acc[bf][1] = __builtin_amdgcn_mfma_f32_16x16x32_bf16(w1, a[bf], acc[bf][1], 0, 0, 0);
      }
#pragma unroll
      for (int bf = 0; bf < 4; ++bf)
#pragma unroll
        for (int ni = 0; ni < 2; ++ni) {
          f32x4 v = acc[bf][ni];
          u64 pk = (u64)cvt_pk(fmaxf(v[0], 0.f), fmaxf(v[1], 0.f))
                 | ((u64)cvt_pk(fmaxf(v[2], 0.f), fmaxf(v[3], 0.f)) << 32);
          *(u64*)(x1 + X_ADDR(bf * 16 + ql, wave * 64 + ni * 32 + qw * 8)) = pk;
        }
    }
    __syncthreads();  // BAR2: x1 ready

    // ---- Phase C: layer 2 (read x1, W2 from L2; write x2) ----
    {
      f32x4 acc[4][2];
#pragma unroll
      for (int ni = 0; ni < 2; ++ni) {
        f32x4 bb = *(const f32x4*)(b2 + wave * 32 + ni * 16 + qw * 4);
#pragma unroll
        for (int bf = 0; bf < 4; ++bf) acc[bf][ni] = bb;
      }
#pragma unroll 4
      for (int kf = 0; kf < 8; ++kf) {
        bf16x8 w0 = *(const bf16x8*)(W2f + (size_t)((kf * 16 + wave * 2 + 0) * 64 + lane) * 8);
        bf16x8 w1 = *(const bf16x8*)(W2f + (size_t)((kf * 16 + wave * 2 + 1) * 64 + lane) * 8);
        bf16x8 a[4];
#pragma unroll
        for (int bf = 0; bf < 4; ++bf)
          a[bf] = *(const bf16x8*)(x1 + X_ADDR(bf * 16 + ql, kf * 64 + qw * 16));
#pragma unroll
        for (int bf = 0; bf < 4; ++bf)
          acc[bf][0] = __builtin_amdgcn_mfma_f32_16x16x32_bf16(w0, a[bf], acc[bf][0], 0, 0, 0);
#pragma unroll
        for (int bf = 0; bf < 4; ++bf)
          acc[bf][1] = __builtin_amdgcn_mfma_f32_16x16x32_bf16(w1, a[bf], acc[bf][1], 0, 0, 0);
      }
#pragma unroll
      for (int bf = 0; bf < 4; ++bf)
#pragma unroll
        for (int ni = 0; ni < 2; ++ni) {
          f32x4 v = acc[bf][ni];
          u64 pk = (u64)cvt_pk(fmaxf(v[0], 0.f), fmaxf(v[1], 0.f))
                 | ((u64)cvt_pk(fmaxf(v[2], 0.f), fmaxf(v[3], 0.f)) << 32);
          *(u64*)(x2 + X_ADDR(bf * 16 + ql, wave * 64 + ni * 32 + qw * 8)) = pk;
        }
    }
    __syncthreads();  // BAR3: x2 ready (x1/ost now dead)

    // ---- Phase A: heads (read x2, Wh from L2) -> ost (LDS, f32) ----
    {
      f32x4 hacc[4];
#pragma unroll
      for (int bf = 0; bf < 4; ++bf) hacc[bf] = hb;
#pragma unroll
      for (int kf = 0; kf < 8; ++kf) {
        bf16x8 w = *(const bf16x8*)(Whf + (size_t)((kf * 8 + wave) * 64 + lane) * 8);
        bf16x8 a[4];
#pragma unroll
        for (int bf = 0; bf < 4; ++bf)
          a[bf] = *(const bf16x8*)(x2 + X_ADDR(bf * 16 + ql, kf * 64 + qw * 16));
#pragma unroll
        for (int bf = 0; bf < 4; ++bf)
          hacc[bf] = __builtin_amdgcn_mfma_f32_16x16x32_bf16(w, a[bf], hacc[bf], 0, 0, 0);
      }
      // thread holds 4 consecutive head cols (f32) at fixed batch -> one b128
#pragma unroll
      for (int bf = 0; bf < 4; ++bf) {
        int row = bf * 16 + ql;                         // batch
        int byte = wave * 64 + qw * 16;                 // hcol*4
        *(f32x4*)(ost + row * 512 + (byte ^ ((row & 7) << 4))) = hacc[bf];
      }
    }
    __syncthreads();  // BAR4: ost ready

    // ---- coalesced NT export (full 256B rows, bypass L2) + stage next pair ----
    for (int i = t; i < 64 * 32; i += 512) {
      int r = i >> 5, c4 = i & 31;
      f32x4 v = *(const f32x4*)(ost + r * 512 + ((c4 * 16) ^ ((r & 7) << 4)));
      size_t off;
      if (c4 < 16)
        off = ((size_t)p * NB + b0 + r) * 64 + (size_t)c4 * 4;
      else
        off = (size_t)3 * NB * 64 + ((size_t)p * NB + b0 + r) * 64 + (size_t)(c4 - 16) * 4;
      __builtin_nontemporal_store(v, (f32x4*)(out + off));
    }
    if (step + 1 < 3 * TPB) {
      const int np = (step + 1) % 3;
      const size_t nb0 = (size_t)(blockIdx.x * TPB + (step + 1) / 3) * 64;
      if (np == 0) {
        for (int i = t; i < 64 * 29; i += 512) {
          int r = i / 29, c4 = i - r * 29;
          const f32x4 v = __builtin_nontemporal_load((const f32x4*)(emb + (nb0 + r) * 116 + c4 * 4));
          u64 pk = (u64)cvt_pk(v[0], v[1]) | ((u64)cvt_pk(v[2], v[3]) << 32);
          *(u64*)(inp + INP_ADDR(r, 24 + 8 * c4)) = pk;
        }
      }
      if (t < 64) {
        const float* isr = init_s + (nb0 + t) * 9;
        const float* csr = cur_s + (nb0 + t) * 9;
        *(u32*)(inp + INP_ADDR(t, 12)) = cvt_pk(isr[IA[np]], isr[IB[np]]);
        *(u32*)(inp + INP_ADDR(t, 16)) = cvt_pk(isr[IC[np]], csr[IA[np]]);
        *(u32*)(inp + INP_ADDR(t, 20)) = cvt_pk(csr[IB[np]], csr[IC[np]]);
      }
    }
    __syncthreads();  // BAR1: inp ready; ost reads done before next x1 writes
  }
}

extern "C" void kernel_launch(void* const* d_in, const int* in_sizes, int n_in,
                              void* d_out, int out_size, void* d_ws, size_t ws_size,
                              hipStream_t stream) {
  (void)in_sizes; (void)n_in; (void)out_size; (void)ws_size;
  const float* init_s = (const float*)d_in[0];
  const float* cur_s  = (const float*)d_in[1];
  const float* emb    = (const float*)d_in[2];
  const float* W1 = (const float*)d_in[3];
  const float* b1 = (const float*)d_in[4];
  const float* W2 = (const float*)d_in[5];
  const float* b2 = (const float*)d_in[6];
  const float* Wm = (const float*)d_in[7];
  const float* bm = (const float*)d_in[8];
  const float* Wv = (const float*)d_in[9];
  const float* bv = (const float*)d_in[10];

  u16* W1f = (u16*)d_ws;
  u16* W2f = (u16*)((char*)d_ws + 65536);
  u16* Whf = (u16*)((char*)d_ws + 196608);
  float* b1p = (float*)((char*)d_ws + 262144);

  prep_kernel<<<128, 256, 0, stream>>>(W1, b1, W2, Wm, Wv, W1f, W2f, Whf, b1p);

  const int lds_bytes = 16384 + 32768 + 32768;  // 80 KB exact -> 2 blocks/CU
  (void)hipFuncSetAttribute((const void*)fused_kernel,
                            hipFuncAttributeMaxDynamicSharedMemorySize, lds_bytes);
  fused_kernel<<<NB / (64 * TPB), 512, lds_bytes, stream>>>(init_s, cur_s, emb, W1f, W2f, Whf,
                                                            b1p, b2, bm, bv, (float*)d_out);
}

// Round 9
// 132.202 us; speedup vs baseline: 1.7581x; 1.6858x over previous
//
#include <hip/hip_runtime.h>

typedef __attribute__((ext_vector_type(8))) __bf16 bf16x8;
typedef __attribute__((ext_vector_type(4))) float f32x4;
typedef unsigned int u32;
typedef unsigned long long u64;
typedef unsigned short u16;

#define NB 131072   // batch
#define TPB 8       // row-tiles per block (grid 256, persistent) — R5-proven config

__device__ __forceinline__ u16 f2bf(float f) {
  unsigned int u = __builtin_bit_cast(unsigned int, f);
  u += 0x7fffu + ((u >> 16) & 1u);
  return (u16)(u >> 16);
}

// pack 2 f32 -> 2 bf16 in one VALU op (RTNE on gfx950; verified R6-R8)
__device__ __forceinline__ u32 cvt_pk(float lo, float hi) {
  u32 r;
  asm("v_cvt_pk_bf16_f32 %0, %1, %2" : "=v"(r) : "v"(lo), "v"(hi));
  return r;
}

// XOR-swizzled LDS addressing (T2)
#define INP_ADDR(r, byte) (((r) << 8) + ((byte) ^ (((r) & 7) << 4)))   // 256 B/row
#define X_ADDR(r, byte)   (((r) << 9) + ((byte) ^ (((r) & 7) << 4)))   // 512 B/row

// ---------------- prep: bf16 frag-ordered weights + per-pair fused bias ----------------
// ws layout: W1f @0 (64KB), W2f @65536 (128KB), Whf @196608 (64KB), b1p @262144 (3KB)
__global__ void prep_kernel(const float* __restrict__ W1, const float* __restrict__ b1,
                            const float* __restrict__ W2,
                            const float* __restrict__ Wm, const float* __restrict__ Wv,
                            u16* __restrict__ W1f, u16* __restrict__ W2f,
                            u16* __restrict__ Whf, float* __restrict__ b1p) {
  int tid = blockIdx.x * 256 + threadIdx.x;
  int NT = gridDim.x * 256;
  for (int i = tid; i < 32768; i += NT) {   // W1f: frag f = kf*16+nf
    int j = i & 7, lane = (i >> 3) & 63, f = i >> 9;
    int nf = f & 15, kf = f >> 4;
    int n = nf * 16 + (lane & 15);
    int k = kf * 32 + 8 * (lane >> 4) + j;
    W1f[i] = f2bf(W1[k * 256 + n]);
  }
  for (int i = tid; i < 65536; i += NT) {   // W2f: f = kf*16+nf
    int j = i & 7, lane = (i >> 3) & 63, f = i >> 9;
    int nf = f & 15, kf = f >> 4;
    int n = nf * 16 + (lane & 15);
    int k = kf * 32 + 8 * (lane >> 4) + j;
    W2f[i] = f2bf(W2[k * 256 + n]);
  }
  for (int i = tid; i < 32768; i += NT) {   // Whf = [Wm | Wv]: f = kf*8+nf
    int j = i & 7, lane = (i >> 3) & 63, f = i >> 9;
    int nf = f & 7, kf = f >> 3;
    int n = nf * 16 + (lane & 15);
    int k = kf * 32 + 8 * (lane >> 4) + j;
    Whf[i] = f2bf(n < 64 ? Wm[k * 64 + n] : Wv[k * 64 + (n - 64)]);
  }
  if (tid < 768) {                          // pairs (0,1),(0,2),(1,2) -> W1 rows {0,4},{0,5},{1,5}
    int p = tid >> 8, h = tid & 255;
    const int r1[3] = {0, 0, 1};
    const int r2[3] = {4, 5, 5};
    b1p[tid] = b1[h] + W1[r1[p] * 256 + h] + W1[r2[p] * 256 + h];
  }
}

// ---------- fused encoder: 8 waves, swapped MFMA (D = W^T X^T), R5 structure + cvt_pk ----------
__global__ __launch_bounds__(512, 2) void fused_kernel(
    const float* __restrict__ init_s, const float* __restrict__ cur_s,
    const float* __restrict__ emb,
    const u16* __restrict__ W1f, const u16* __restrict__ W2f,
    const u16* __restrict__ Whf,
    const float* __restrict__ b1p, const float* __restrict__ b2,
    const float* __restrict__ bm, const float* __restrict__ bv,
    float* __restrict__ out) {
  extern __shared__ char smem[];
  char* inp = smem;            // [64][128] bf16 swizzled (16 KB)
  char* x1  = smem + 16384;    // [64][256] bf16 swizzled (32 KB); ost aliases
  char* x2  = smem + 49152;    // [64][256] bf16 swizzled (32 KB)
  char* ost = x1;              // [64 batch][128 hcol] f32 swizzled (32 KB)
  float* sbI = (float*)(smem + 81920);          // [64][9] init_s tile
  float* sbC = (float*)(smem + 81920 + 2304);   // [64][9] cur_s tile

  const int t = threadIdx.x;
  const int lane = t & 63;
  const int wave = t >> 6;     // 0..7: owns 32 n-cols of L1/L2, 16 head cols
  const int ql = lane & 15, qw = lane >> 4;

  // ---- weights in registers (A-operand after swap): compiler balances residency ----
  bf16x8 w1r[4][2];
#pragma unroll
  for (int kf = 0; kf < 4; ++kf)
#pragma unroll
    for (int ni = 0; ni < 2; ++ni)
      w1r[kf][ni] = *(const bf16x8*)(W1f + (size_t)((kf * 16 + wave * 2 + ni) * 64 + lane) * 8);
  bf16x8 w2r[8][2];
#pragma unroll
  for (int kf = 0; kf < 8; ++kf)
#pragma unroll
    for (int ni = 0; ni < 2; ++ni)
      w2r[kf][ni] = *(const bf16x8*)(W2f + (size_t)((kf * 16 + wave * 2 + ni) * 64 + lane) * 8);
  bf16x8 whr[8];
#pragma unroll
  for (int kf = 0; kf < 8; ++kf)
    whr[kf] = *(const bf16x8*)(Whf + (size_t)((kf * 8 + wave) * 64 + lane) * 8);

  // head bias: n = wave*16 + qw*4 + r (4 consecutive, never straddles 64)
  const int hn = wave * 16 + qw * 4;
  const f32x4 hbv = (hn < 64) ? *(const f32x4*)(bm + hn) : *(const f32x4*)(bv + hn - 64);

  if (t < 64) {  // one-hot-folded cols 0..5 are always zero
    *(u64*)(inp + INP_ADDR(t, 0)) = 0ull;
    *(u32*)(inp + INP_ADDR(t, 8)) = 0u;
  }

  const int IA[3] = {0, 1, 2};
  const int IB[3] = {3, 5, 7};
  const int IC[3] = {4, 6, 8};

#pragma unroll 1
  for (int it = 0; it < TPB; ++it) {
    const int b0 = (blockIdx.x * TPB + it) * 64;

    // ---- tile staging: embeddings -> inp cols 12..127; s tiles -> sbI/sbC ----
    for (int i = t; i < 64 * 29; i += 512) {
      int r = i / 29;
      int c4 = i - r * 29;
      const f32x4 v = __builtin_nontemporal_load((const f32x4*)(emb + (size_t)(b0 + r) * 116 + c4 * 4));
      u64 pk = (u64)cvt_pk(v[0], v[1]) | ((u64)cvt_pk(v[2], v[3]) << 32);
      *(u64*)(inp + INP_ADDR(r, 24 + 8 * c4)) = pk;
    }
    if (t < 288) {  // 64 rows x 9 floats = 144 float4 each, fully coalesced
      int which = t >= 144;
      int idx = which ? t - 144 : t;
      const float* src = which ? cur_s : init_s;
      float* dst = which ? sbC : sbI;
      ((float4*)dst)[idx] = ((const float4*)(src + (size_t)b0 * 9))[idx];
    }

#pragma unroll 1
    for (int p = 0; p < 3; ++p) {
      if (p == 0) __syncthreads();  // staging visible
      if (t < 64) {  // s-feature cols 6..11 from LDS-staged s tiles
        float a0 = sbI[t * 9 + IA[p]], a1 = sbI[t * 9 + IB[p]], a2 = sbI[t * 9 + IC[p]];
        float c0 = sbC[t * 9 + IA[p]], c1 = sbC[t * 9 + IB[p]], c2 = sbC[t * 9 + IC[p]];
        *(u32*)(inp + INP_ADDR(t, 12)) = cvt_pk(a0, a1);
        *(u32*)(inp + INP_ADDR(t, 16)) = cvt_pk(a2, c0);
        *(u32*)(inp + INP_ADDR(t, 20)) = cvt_pk(c1, c2);
      }
      __syncthreads();

      // ---- layer 1: D = W1^T X^T; wave owns n cols [wave*32, +32) ----
      {
        f32x4 acc[4][2];   // [batch-frag][n-frag]; reg r = n = base + qw*4 + r
#pragma unroll
        for (int ni = 0; ni < 2; ++ni) {
          f32x4 bb = *(const f32x4*)(b1p + p * 256 + wave * 32 + ni * 16 + qw * 4);
#pragma unroll
          for (int bf = 0; bf < 4; ++bf) acc[bf][ni] = bb;
        }
#pragma unroll
        for (int kf = 0; kf < 4; ++kf) {
          bf16x8 b[4];
#pragma unroll
          for (int bf = 0; bf < 4; ++bf)
            b[bf] = *(const bf16x8*)(inp + INP_ADDR(bf * 16 + ql, kf * 64 + qw * 16));
#pragma unroll
          for (int ni = 0; ni < 2; ++ni)
#pragma unroll
            for (int bf = 0; bf < 4; ++bf)
              acc[bf][ni] = __builtin_amdgcn_mfma_f32_16x16x32_bf16(w1r[kf][ni], b[bf], acc[bf][ni], 0, 0, 0);
        }
        // writeback: thread holds 4 consecutive n at fixed batch -> one b64 per frag
#pragma unroll
        for (int bf = 0; bf < 4; ++bf)
#pragma unroll
          for (int ni = 0; ni < 2; ++ni) {
            f32x4 v = acc[bf][ni];
            u64 pk = (u64)cvt_pk(fmaxf(v[0], 0.f), fmaxf(v[1], 0.f))
                   | ((u64)cvt_pk(fmaxf(v[2], 0.f), fmaxf(v[3], 0.f)) << 32);
            *(u64*)(x1 + X_ADDR(bf * 16 + ql, wave * 64 + ni * 32 + qw * 8)) = pk;
          }
      }
      __syncthreads();

      // ---- layer 2: x1 -> x2 ----
      {
        f32x4 acc[4][2];
#pragma unroll
        for (int ni = 0; ni < 2; ++ni) {
          f32x4 bb = *(const f32x4*)(b2 + wave * 32 + ni * 16 + qw * 4);
#pragma unroll
          for (int bf = 0; bf < 4; ++bf) acc[bf][ni] = bb;
        }
#pragma unroll
        for (int kf = 0; kf < 8; ++kf) {
          bf16x8 b[4];
#pragma unroll
          for (int bf = 0; bf < 4; ++bf)
            b[bf] = *(const bf16x8*)(x1 + X_ADDR(bf * 16 + ql, kf * 64 + qw * 16));
#pragma unroll
          for (int ni = 0; ni < 2; ++ni)
#pragma unroll
            for (int bf = 0; bf < 4; ++bf)
              acc[bf][ni] = __builtin_amdgcn_mfma_f32_16x16x32_bf16(w2r[kf][ni], b[bf], acc[bf][ni], 0, 0, 0);
        }
#pragma unroll
        for (int bf = 0; bf < 4; ++bf)
#pragma unroll
          for (int ni = 0; ni < 2; ++ni) {
            f32x4 v = acc[bf][ni];
            u64 pk = (u64)cvt_pk(fmaxf(v[0], 0.f), fmaxf(v[1], 0.f))
                   | ((u64)cvt_pk(fmaxf(v[2], 0.f), fmaxf(v[3], 0.f)) << 32);
            *(u64*)(x2 + X_ADDR(bf * 16 + ql, wave * 64 + ni * 32 + qw * 8)) = pk;
          }
      }
      __syncthreads();

      // ---- heads: x2 @ [Wm|Wv]; wave owns head cols [wave*16, +16) ----
      {
        f32x4 hacc[4];
#pragma unroll
        for (int bf = 0; bf < 4; ++bf) hacc[bf] = hbv;
#pragma unroll
        for (int kf = 0; kf < 8; ++kf) {
          bf16x8 b[4];
#pragma unroll
          for (int bf = 0; bf < 4; ++bf)
            b[bf] = *(const bf16x8*)(x2 + X_ADDR(bf * 16 + ql, kf * 64 + qw * 16));
#pragma unroll
          for (int bf = 0; bf < 4; ++bf)
            hacc[bf] = __builtin_amdgcn_mfma_f32_16x16x32_bf16(whr[kf], b[bf], hacc[bf], 0, 0, 0);
        }
        // thread holds 4 consecutive head cols (f32) at fixed batch -> one b128
#pragma unroll
        for (int bf = 0; bf < 4; ++bf) {
          int row = bf * 16 + ql;                         // batch
          int byte = wave * 64 + qw * 16;                 // hcol*4
          *(f32x4*)(ost + row * 512 + (byte ^ ((row & 7) << 4))) = hacc[bf];
        }
      }
      __syncthreads();

      // ---- coalesced NT export: cols 0-63 -> means, 64-127 -> log_vars ----
      for (int i = t; i < 64 * 32; i += 512) {
        int r = i >> 5, c4 = i & 31;
        f32x4 v = *(const f32x4*)(ost + r * 512 + ((c4 * 16) ^ ((r & 7) << 4)));
        size_t off;
        if (c4 < 16)
          off = ((size_t)p * NB + b0 + r) * 64 + (size_t)c4 * 4;
        else
          off = (size_t)3 * NB * 64 + ((size_t)p * NB + b0 + r) * 64 + (size_t)(c4 - 16) * 4;
        __builtin_nontemporal_store(v, (f32x4*)(out + off));
      }
      // next iteration's post-s-feat barrier orders ost reads vs next x1 writes
    }
  }
}

extern "C" void kernel_launch(void* const* d_in, const int* in_sizes, int n_in,
                              void* d_out, int out_size, void* d_ws, size_t ws_size,
                              hipStream_t stream) {
  (void)in_sizes; (void)n_in; (void)out_size; (void)ws_size;
  const float* init_s = (const float*)d_in[0];
  const float* cur_s  = (const float*)d_in[1];
  const float* emb    = (const float*)d_in[2];
  const float* W1 = (const float*)d_in[3];
  const float* b1 = (const float*)d_in[4];
  const float* W2 = (const float*)d_in[5];
  const float* b2 = (const float*)d_in[6];
  const float* Wm = (const float*)d_in[7];
  const float* bm = (const float*)d_in[8];
  const float* Wv = (const float*)d_in[9];
  const float* bv = (const float*)d_in[10];

  u16* W1f = (u16*)d_ws;
  u16* W2f = (u16*)((char*)d_ws + 65536);
  u16* Whf = (u16*)((char*)d_ws + 196608);
  float* b1p = (float*)((char*)d_ws + 262144);

  prep_kernel<<<128, 256, 0, stream>>>(W1, b1, W2, Wm, Wv, W1f, W2f, Whf, b1p);

  const int lds_bytes = 16384 + 32768 + 32768 + 4608;  // 86528 — R5-proven
  (void)hipFuncSetAttribute((const void*)fused_kernel,
                            hipFuncAttributeMaxDynamicSharedMemorySize, lds_bytes);
  fused_kernel<<<NB / (64 * TPB), 512, lds_bytes, stream>>>(init_s, cur_s, emb, W1f, W2f, Whf,
                                                            b1p, b2, bm, bv, (float*)d_out);
}